// Round 11
// baseline (189.458 us; speedup 1.0000x reference)
//
#include <hip/hip_runtime.h>
#include <stdint.h>

typedef unsigned short u16;
typedef unsigned long long u64;
using short8 = __attribute__((ext_vector_type(8))) short;
using f32x16 = __attribute__((ext_vector_type(16))) float;
using f32x4v = __attribute__((ext_vector_type(4))) float;

#define NROWS 65536
#define DIM   512
#define KC    1024

#define GLOBAL_AS __attribute__((address_space(1)))
#define LDS_AS    __attribute__((address_space(3)))

__device__ __forceinline__ void gload_lds16(const void* g, void* l) {
  __builtin_amdgcn_global_load_lds((const GLOBAL_AS uint32_t*)g,
                                   (LDS_AS uint32_t*)l, 16, 0, 0);
}

__device__ __forceinline__ u16 f2bf(float f) {  // RNE float->bf16 bits
  unsigned u = __float_as_uint(f);
  return (u16)((u + 0x7fffu + ((u >> 16) & 1u)) >> 16);
}

__device__ __forceinline__ f32x4v ntload4(const float* p) {
  return __builtin_nontemporal_load((const f32x4v*)p);
}
__device__ __forceinline__ void ntstore4(float* p, f32x4v v) {
  __builtin_nontemporal_store(v, (f32x4v*)p);
}

// ---- W prep: W^T in MFMA-B-fragment order (32-code tiles) + ||w||^2 -------
__global__ __launch_bounds__(256) void wprep_kernel(const float* __restrict__ W,
                                                    short8* __restrict__ WhT8,
                                                    float* __restrict__ wnorm,
                                                    int* __restrict__ counts,
                                                    double* __restrict__ sums) {
  if (blockIdx.x == 0) {
    for (int k = threadIdx.x; k < KC; k += 256) counts[k] = 0;
    if (threadIdx.x < 2) sums[threadIdx.x] = 0.0;
  }
  int code = blockIdx.x * 4 + (threadIdx.x >> 6);
  int l = threadIdx.x & 63;
  const float* wr = W + (size_t)code * DIM + l * 8;
  float4 v0 = *(const float4*)wr;
  float4 v1 = *(const float4*)(wr + 4);
  float s = v0.x * v0.x + v0.y * v0.y + v0.z * v0.z + v0.w * v0.w
          + v1.x * v1.x + v1.y * v1.y + v1.z * v1.z + v1.w * v1.w;
  short8 pk;
  pk[0] = (short)f2bf(v0.x); pk[1] = (short)f2bf(v0.y);
  pk[2] = (short)f2bf(v0.z); pk[3] = (short)f2bf(v0.w);
  pk[4] = (short)f2bf(v1.x); pk[5] = (short)f2bf(v1.y);
  pk[6] = (short)f2bf(v1.z); pk[7] = (short)f2bf(v1.w);
  WhT8[(size_t)(code >> 5) * 2048 + (l >> 1) * 64 + (l & 1) * 32 + (code & 31)] = pk;
#pragma unroll
  for (int off = 32; off; off >>= 1) s += __shfl_xor(s, off, 64);
  if (l == 0) wnorm[code] = s;
}

// ---- K1: distances + argmin + stats + enc-zero stream ---------------------
// 256 thr = 4 waves x 32 rows; grid 512 = 2 blocks/CU. A in regs; B via
// double-buffered LDS DMA; inner loop uses an explicit 8-deep ds_read ring.
__global__ __launch_bounds__(256)
__attribute__((amdgpu_waves_per_eu(2, 2))) void mm_kernel(
    const float* __restrict__ X, const u16* __restrict__ WhTf,
    const float* __restrict__ wnorm, int* __restrict__ best_idx,
    int* __restrict__ counts, double* __restrict__ sums,
    float* __restrict__ encf) {
  __shared__ __align__(16) u16 BsU[2][16384];  // 2 x 32 KB
  __shared__ double sdbl[4];
  const int t = threadIdx.x;
  const int w = t >> 6, l = t & 63;
  const int r = l & 31, h = l >> 5;
  const int row0 = blockIdx.x * 128;

  // kick off tile 0 DMA
#pragma unroll
  for (int i = 0; i < 8; ++i)
    gload_lds16(WhTf + i * 2048 + t * 8, &BsU[0][i * 2048 + t * 8]);

  // A panel (32 rows x 512) -> regs as MFMA A-frags (NT loads), sum(x^2)
  const float* Xr = X + (size_t)(row0 + w * 32 + r) * DIM + h * 8;
  short8 aF[32];
  double xacc = 0.0;
#pragma unroll
  for (int s = 0; s < 32; ++s) {
    f32x4v v0 = ntload4(Xr + s * 16);
    f32x4v v1 = ntload4(Xr + s * 16 + 4);
    xacc += (double)v0[0] * v0[0] + (double)v0[1] * v0[1] + (double)v0[2] * v0[2] + (double)v0[3] * v0[3]
          + (double)v1[0] * v1[0] + (double)v1[1] * v1[1] + (double)v1[2] * v1[2] + (double)v1[3] * v1[3];
    short8 pk;
    pk[0] = (short)f2bf(v0[0]); pk[1] = (short)f2bf(v0[1]);
    pk[2] = (short)f2bf(v0[2]); pk[3] = (short)f2bf(v0[3]);
    pk[4] = (short)f2bf(v1[0]); pk[5] = (short)f2bf(v1[1]);
    pk[6] = (short)f2bf(v1[2]); pk[7] = (short)f2bf(v1[3]);
    aF[s] = pk;
  }
#pragma unroll
  for (int off = 32; off; off >>= 1) xacc += __shfl_xor(xacc, off, 64);
  if (l == 0) atomicAdd(&sums[0], xacc);

  unsigned best_[16];
#pragma unroll
  for (int q = 0; q < 16; ++q) best_[q] = 0xFFFFFFFFu;

  f32x4v* encz = (f32x4v*)(encf + (size_t)row0 * KC);
  const f32x4v zero4 = {0.f, 0.f, 0.f, 0.f};

  asm volatile("s_waitcnt vmcnt(0)" ::: "memory");
  __builtin_amdgcn_s_barrier();
  __builtin_amdgcn_sched_barrier(0);

  for (int kt = 0; kt < 32; ++kt) {
    const int buf = kt & 1;
    if (kt < 31) {  // prefetch next tile DMA (oldest vmcnt entries)
      const u16* src = WhTf + (size_t)(kt + 1) * 16384;
#pragma unroll
      for (int i = 0; i < 8; ++i)
        gload_lds16(src + i * 2048 + t * 8, &BsU[buf ^ 1][i * 2048 + t * 8]);
    }
    // enc-zero stream, NT (newest vmcnt entries; excluded from the drain)
#pragma unroll
    for (int j = 0; j < 4; ++j)
      __builtin_nontemporal_store(zero4, &encz[kt * 1024 + j * 256 + t]);

    const u16* bufp = &BsU[buf][l * 8];
    // explicit 8-deep B-fragment ring: hides ~120cyc LDS latency under MFMAs
    short8 bv[8];
#pragma unroll
    for (int i = 0; i < 8; ++i) bv[i] = *(const short8*)&bufp[i * 512];
    f32x16 acc_e = {}, acc_o = {};
#pragma unroll
    for (int ks = 0; ks < 32; ++ks) {
      if (ks & 1)
        acc_o = __builtin_amdgcn_mfma_f32_32x32x16_bf16(aF[ks], bv[ks & 7], acc_o, 0, 0, 0);
      else
        acc_e = __builtin_amdgcn_mfma_f32_32x32x16_bf16(aF[ks], bv[ks & 7], acc_e, 0, 0, 0);
      if (ks < 24) bv[ks & 7] = *(const short8*)&bufp[(ks + 8) * 512];
    }
    float wn = wnorm[kt * 32 + r];
    unsigned col = (unsigned)(kt * 32 + r);
#pragma unroll
    for (int q = 0; q < 16; ++q) {
      float sc = fmaf(-2.0f, acc_e[q] + acc_o[q], wn);
      unsigned u_ = __float_as_uint(sc);
      unsigned key = (u_ & 0x80000000u) ? ~u_ : (u_ | 0x80000000u);
      best_[q] = min(best_[q], (key & 0xFFFFFC00u) | col);
    }
    asm volatile("s_waitcnt vmcnt(4)" ::: "memory");  // drain the 8 gloads
    __builtin_amdgcn_s_barrier();
    __builtin_amdgcn_sched_barrier(0);
  }

  // per-row argmin across the 32 code-lanes; write best_idx + stats
  double local = 0.0;
#pragma unroll
  for (int q = 0; q < 16; ++q) {
    unsigned pb = best_[q];
#pragma unroll
    for (int off = 16; off; off >>= 1)
      pb = min(pb, (unsigned)__shfl_xor((int)pb, off, 32));
    if (r == 0) {
      int row = row0 + w * 32 + (q & 3) + 8 * (q >> 2) + 4 * h;
      int k = (int)(pb & 1023u);
      best_idx[row] = k;
      atomicAdd(&counts[k], 1);
      unsigned key = (pb & 0xFFFFFC00u) | 0x200u;  // midpoint reconstruction
      unsigned uu = (key & 0x80000000u) ? (key ^ 0x80000000u) : ~key;
      local += (double)__uint_as_float(uu);
    }
  }
  {
    double o32 = __shfl(local, 32, 64);
    if (l == 0) sdbl[w] = local + o32;
  }
  __syncthreads();
  if (t == 0) atomicAdd(&sums[1], sdbl[0] + sdbl[1] + sdbl[2] + sdbl[3]);
}

// ---- K2: quantized gather-write + one-hot 1.0 scatter ---------------------
// 2048 blocks x 32 rows. Aligned float4 NT stores around the +1 output base.
__global__ __launch_bounds__(256) void out_kernel(const float* __restrict__ W,
                                                  const int* __restrict__ best_idx,
                                                  float* __restrict__ out,
                                                  float* __restrict__ encf) {
  const int t = threadIdx.x;
  const int w = t >> 6, l = t & 63;
#pragma unroll
  for (int j = 0; j < 8; ++j) {
    int rr = blockIdx.x * 32 + w * 8 + j;
    int k = best_idx[rr];
    const float* Wr = W + (size_t)k * DIM;
    size_t ob = (size_t)rr * DIM;
    {
      f32x4v cm = *(const f32x4v*)(Wr + 4 * l);
      f32x4v c1 = *(const f32x4v*)(Wr + 4 * l + 4);
      f32x4v sv = {cm[3], c1[0], c1[1], c1[2]};
      ntstore4(out + ob + 4 + 4 * l, sv);
    }
    if (l <= 62) {
      int m = l + 64;
      f32x4v dm = *(const f32x4v*)(Wr + 4 * m);
      f32x4v d1 = *(const f32x4v*)(Wr + 4 * m + 4);
      f32x4v sv = {dm[3], d1[0], d1[1], d1[2]};
      ntstore4(out + ob + 4 + 4 * m, sv);
    }
    if (l < 3) out[ob + 1 + l] = Wr[l];        // head d=0,1,2
    if (l == 3) out[ob + 512] = Wr[511];       // tail d=511
    if (l == 4) encf[(size_t)rr * KC + k] = 1.0f;  // one-hot (zeros from K1)
  }
}

// ---- finalize: loss + perplexity ------------------------------------------
__global__ __launch_bounds__(256) void finalize_kernel(
    const int* __restrict__ counts, const double* __restrict__ sums,
    float* __restrict__ out_loss, float* __restrict__ out_perp) {
  __shared__ float red[4];
  int t = threadIdx.x;
  float h = 0.f;
  for (int k = t; k < KC; k += 256) {
    float p = (float)counts[k] / (float)NROWS;
    h -= p * logf(p + 1e-10f);
  }
#pragma unroll
  for (int off = 32; off; off >>= 1) h += __shfl_xor(h, off, 64);
  if ((t & 63) == 0) red[t >> 6] = h;
  __syncthreads();
  if (t == 0) {
    float H = red[0] + red[1] + red[2] + red[3];
    *out_perp = expf(H);
    double m = (sums[0] + sums[1]) / (double)((long long)NROWS * DIM);
    *out_loss = (float)(1.25 * m);
  }
}

extern "C" void kernel_launch(void* const* d_in, const int* in_sizes, int n_in,
                              void* d_out, int out_size, void* d_ws, size_t ws_size,
                              hipStream_t stream) {
  const float* X = (const float*)d_in[0];
  const float* W = (const float*)d_in[1];
  float* out = (float*)d_out;
  char* ws = (char*)d_ws;

  float* out_loss = out;                     // [0]
  float* out_perp = out + 1 + NROWS * DIM;   // [33554433]
  float* encf     = out + 2 + NROWS * DIM;   // [33554434 ..)

  short8* WhT8    = (short8*)ws;                          // 1 MB
  float*  wnorm   = (float*)(ws + (1040u << 10));         // 4 KB
  int*    counts  = (int*)(ws + (1040u << 10) + 4096);    // 4 KB
  double* sums    = (double*)(ws + (1040u << 10) + 8192); // 16 B
  int*    best_idx= (int*)(ws + (1040u << 10) + 12288);   // 256 KB

  wprep_kernel<<<KC / 4, 256, 0, stream>>>(W, WhT8, wnorm, counts, sums);
  mm_kernel<<<NROWS / 128, 256, 0, stream>>>(X, (const u16*)WhT8, wnorm,
                                             best_idx, counts, sums, encf);
  out_kernel<<<NROWS / 32, 256, 0, stream>>>(W, best_idx, out, encf);
  finalize_kernel<<<1, 256, 0, stream>>>(counts, sums, out_loss, out_perp);
}